// Round 3
// baseline (42.997 us; speedup 1.0000x reference)
//
#include <hip/hip_runtime.h>
#include <math.h>

// Problem constants (from reference):
constexpr int Bn = 1024;
constexpr int S  = 512;
constexpr int H  = 768;
constexpr int D1 = 128;
constexpr int HV = H / 4;     // 192 float4 per feature row
constexpr int CH = 8;         // d-chunks in head (192 rows each)

// ws layout (floats):
//   gcat [Bn][1536]  — concat [cls | span-mean] per example (6 MB)
//   P    [CH][Bn][D1] — per-d-chunk partial h dots (4 MB)

// Kernel 1: CLS extract + ragged span mean-pool, 1 block/example.
// 8 independent float4 accumulators -> 8 loads in flight per wave.
__global__ __launch_bounds__(192) void pool_kernel(
    const float* __restrict__ feat, const int* __restrict__ start,
    const int* __restrict__ endp, float* __restrict__ gcat) {
  const int b = blockIdx.x;
  const int t = threadIdx.x;  // one float4 column
  const float4* base = reinterpret_cast<const float4*>(feat) + (size_t)b * (S * HV);

  float4 cls = base[t];  // row 0

  const int s0 = start[b];
  const int s1 = endp[b];
  float4 a0{0,0,0,0}, a1{0,0,0,0}, a2{0,0,0,0}, a3{0,0,0,0};
  float4 a4{0,0,0,0}, a5{0,0,0,0}, a6{0,0,0,0}, a7{0,0,0,0};
  int s = s0;
  for (; s + 7 < s1; s += 8) {
    float4 v0 = base[(size_t)(s + 0) * HV + t];
    float4 v1 = base[(size_t)(s + 1) * HV + t];
    float4 v2 = base[(size_t)(s + 2) * HV + t];
    float4 v3 = base[(size_t)(s + 3) * HV + t];
    float4 v4 = base[(size_t)(s + 4) * HV + t];
    float4 v5 = base[(size_t)(s + 5) * HV + t];
    float4 v6 = base[(size_t)(s + 6) * HV + t];
    float4 v7 = base[(size_t)(s + 7) * HV + t];
    a0.x += v0.x; a0.y += v0.y; a0.z += v0.z; a0.w += v0.w;
    a1.x += v1.x; a1.y += v1.y; a1.z += v1.z; a1.w += v1.w;
    a2.x += v2.x; a2.y += v2.y; a2.z += v2.z; a2.w += v2.w;
    a3.x += v3.x; a3.y += v3.y; a3.z += v3.z; a3.w += v3.w;
    a4.x += v4.x; a4.y += v4.y; a4.z += v4.z; a4.w += v4.w;
    a5.x += v5.x; a5.y += v5.y; a5.z += v5.z; a5.w += v5.w;
    a6.x += v6.x; a6.y += v6.y; a6.z += v6.z; a6.w += v6.w;
    a7.x += v7.x; a7.y += v7.y; a7.z += v7.z; a7.w += v7.w;
  }
  for (; s < s1; ++s) {
    float4 v = base[(size_t)s * HV + t];
    a0.x += v.x; a0.y += v.y; a0.z += v.z; a0.w += v.w;
  }
  const float inv = 1.0f / (float)(s1 - s0);
  float4 r;
  r.x = (((a0.x + a1.x) + (a2.x + a3.x)) + ((a4.x + a5.x) + (a6.x + a7.x))) * inv;
  r.y = (((a0.y + a1.y) + (a2.y + a3.y)) + ((a4.y + a5.y) + (a6.y + a7.y))) * inv;
  r.z = (((a0.z + a1.z) + (a2.z + a3.z)) + ((a4.z + a5.z) + (a6.z + a7.z))) * inv;
  r.w = (((a0.w + a1.w) + (a2.w + a3.w)) + ((a4.w + a5.w) + (a6.w + a7.w))) * inv;

  float4* Gv = reinterpret_cast<float4*>(gcat) + (size_t)b * (2 * HV);
  Gv[t] = cls;        // cls half [0,768)
  Gv[HV + t] = r;     // crc half [768,1536)
}

// Kernel 2: partial W1 dots. Block = 16 examples x 192-row d-chunk.
// Wave owns 4 examples; g reads are wave-uniform -> scalar (SMEM) loads.
// Lane l owns output pair k = (2l, 2l+1) via one coalesced dwordx2 of W1 per d.
__global__ __launch_bounds__(256) void head_partial(
    const float* __restrict__ gcat, const float* __restrict__ W1,
    float* __restrict__ P) {
  const int t  = threadIdx.x;
  const int l  = t & 63;
  const int wv = t >> 6;                 // wave 0..3
  const int c  = blockIdx.x & (CH - 1);  // d-chunk 0..7
  const int eg = blockIdx.x / CH;        // 0..63
  const int d0 = c * 192;
  const int e0 = eg * 16 + wv * 4;       // this wave's 4 examples

  // wave-uniform g bases (force scalar path)
  const int go = __builtin_amdgcn_readfirstlane(e0 * (2 * H) + d0);
  const float* g0 = gcat + go;
  const float* g1 = g0 + 2 * H;
  const float* g2 = g1 + 2 * H;
  const float* g3 = g2 + 2 * H;

  const float2* Wv = reinterpret_cast<const float2*>(W1 + (size_t)d0 * D1) + l;

  float ax0 = 0.f, ay0 = 0.f, ax1 = 0.f, ay1 = 0.f;
  float ax2 = 0.f, ay2 = 0.f, ax3 = 0.f, ay3 = 0.f;
  #pragma unroll 4
  for (int d = 0; d < 192; ++d) {
    float2 w = Wv[(size_t)d * (D1 / 2)];   // coalesced 512B/wave per d
    float q0 = g0[d];                       // scalar loads (uniform addr)
    float q1 = g1[d];
    float q2 = g2[d];
    float q3 = g3[d];
    ax0 += q0 * w.x; ay0 += q0 * w.y;
    ax1 += q1 * w.x; ay1 += q1 * w.y;
    ax2 += q2 * w.x; ay2 += q2 * w.y;
    ax3 += q3 * w.x; ay3 += q3 * w.y;
  }

  float2* Pp = reinterpret_cast<float2*>(P + ((size_t)c * Bn + e0) * D1) + l;
  Pp[0 * (D1 / 2)] = make_float2(ax0, ay0);
  Pp[1 * (D1 / 2)] = make_float2(ax1, ay1);
  Pp[2 * (D1 / 2)] = make_float2(ax2, ay2);
  Pp[3 * (D1 / 2)] = make_float2(ax3, ay3);
}

// Kernel 3: combine chunks, relu, dot W2, sigmoid. One wave per example.
__global__ __launch_bounds__(256) void finalize(
    const float* __restrict__ P, const float* __restrict__ b1,
    const float* __restrict__ W2, const float* __restrict__ b2,
    float* __restrict__ out) {
  const int t = threadIdx.x;
  const int w = t >> 6, l = t & 63;
  const int e = blockIdx.x * 4 + w;
  const int k0 = l, k1 = l + 64;
  float h0 = b1[k0], h1 = b1[k1];
  #pragma unroll
  for (int c = 0; c < CH; ++c) {
    h0 += P[((size_t)c * Bn + e) * D1 + k0];
    h1 += P[((size_t)c * Bn + e) * D1 + k1];
  }
  h0 = fmaxf(h0, 0.f); h1 = fmaxf(h1, 0.f);
  float v = h0 * W2[k0] + h1 * W2[k1];
  #pragma unroll
  for (int off = 32; off > 0; off >>= 1) v += __shfl_down(v, off);
  if (l == 0) out[e] = 1.0f / (1.0f + expf(-(v + b2[0])));
}

extern "C" void kernel_launch(void* const* d_in, const int* in_sizes, int n_in,
                              void* d_out, int out_size, void* d_ws, size_t ws_size,
                              hipStream_t stream) {
  const float* feat = (const float*)d_in[0];   // [B,S,H] fp32
  const int* start  = (const int*)d_in[1];     // [B]
  const int* endp   = (const int*)d_in[2];     // [B]
  const float* W1   = (const float*)d_in[3];   // [2H,D1]
  const float* b1   = (const float*)d_in[4];   // [D1]
  const float* W2   = (const float*)d_in[5];   // [D1,1]
  const float* b2   = (const float*)d_in[6];   // [1]
  float* out = (float*)d_out;                  // [B]

  float* wsf  = (float*)d_ws;
  float* gcat = wsf;                           // [Bn][1536]
  float* P    = gcat + (size_t)Bn * 2 * H;     // [CH][Bn][D1]

  hipLaunchKernelGGL(pool_kernel, dim3(Bn), dim3(192), 0, stream,
                     feat, start, endp, gcat);
  hipLaunchKernelGGL(head_partial, dim3((Bn / 16) * CH), dim3(256), 0, stream,
                     gcat, W1, P);
  hipLaunchKernelGGL(finalize, dim3(Bn / 4), dim3(256), 0, stream,
                     P, b1, W2, b2, out);
}